// Round 1
// baseline (462.994 us; speedup 1.0000x reference)
//
#include <hip/hip_runtime.h>

// ---------------------------------------------------------------------------
// OseroNetworks: out[b] = mlp3_e(edge[b]).sum + mlp3_x(cross[b]).sum
//                        + mlp3_c(corner[b]).sum + cn[b]*nW + nb
// Memory-bound: 456 B/elem vs ~2226 FMA/elem (9.8 F/B < 25 F/B balance).
// One thread per element, float4 loads, weights broadcast from LDS.
// ---------------------------------------------------------------------------

// LDS layout (float offsets). 10-wide weight rows padded to 12 (48 B) so every
// row is 16B-aligned -> ds_read_b128-able. 8x8 rows are naturally 32 B.
#define OFF_EW1 0
#define OFF_EW2 120
#define OFF_CW1 240
#define OFF_CW2 360
#define OFF_XW1 480
#define OFF_XW2 544
#define OFF_EW3 608
#define OFF_CW3 618
#define OFF_XW3 628
#define OFF_EB1 636
#define OFF_EB2 646
#define OFF_CB1 656
#define OFF_CB2 666
#define OFF_XB1 676
#define OFF_XB2 684
#define OFF_SC  692   // [0]=eb3 [1]=cb3 [2]=xb3 [3]=nW [4]=nb
#define SMEM_TOT 700

// x: [4][D] flat. W1,W2: LDS, rows padded to P. Returns sum over the 4 slices
// of (W3 . relu(W2 . relu(W1.x + b1) + b2)) + 4*b3.
template<int D, int P>
__device__ __forceinline__ float mlp3_sum4(const float* __restrict__ x,
                                           const float* __restrict__ W1,
                                           const float* __restrict__ b1,
                                           const float* __restrict__ W2,
                                           const float* __restrict__ b2,
                                           const float* __restrict__ W3,
                                           float b3)
{
    float h1[4 * D];
    #pragma unroll
    for (int o = 0; o < D; ++o) {
        float w[D];
        #pragma unroll
        for (int i = 0; i < D; ++i) w[i] = W1[o * P + i];
        const float bb = b1[o];
        #pragma unroll
        for (int s = 0; s < 4; ++s) {
            float acc = bb;
            #pragma unroll
            for (int i = 0; i < D; ++i) acc = fmaf(w[i], x[s * D + i], acc);
            h1[s * D + o] = fmaxf(acc, 0.0f);
        }
    }
    float h2[4 * D];
    #pragma unroll
    for (int o = 0; o < D; ++o) {
        float w[D];
        #pragma unroll
        for (int i = 0; i < D; ++i) w[i] = W2[o * P + i];
        const float bb = b2[o];
        #pragma unroll
        for (int s = 0; s < 4; ++s) {
            float acc = bb;
            #pragma unroll
            for (int i = 0; i < D; ++i) acc = fmaf(w[i], h1[s * D + i], acc);
            h2[s * D + o] = fmaxf(acc, 0.0f);
        }
    }
    float out = 4.0f * b3;
    #pragma unroll
    for (int i = 0; i < D; ++i) {
        const float w = W3[i];
        #pragma unroll
        for (int s = 0; s < 4; ++s) out = fmaf(w, h2[s * D + i], out);
    }
    return out;
}

__global__ __launch_bounds__(256)
void osero_kernel(const float* __restrict__ edge,
                  const float* __restrict__ cross_,
                  const float* __restrict__ corner,
                  const float* __restrict__ cn,
                  const float* __restrict__ eW1, const float* __restrict__ eb1,
                  const float* __restrict__ eW2, const float* __restrict__ eb2,
                  const float* __restrict__ eW3, const float* __restrict__ eb3,
                  const float* __restrict__ xW1, const float* __restrict__ xb1,
                  const float* __restrict__ xW2, const float* __restrict__ xb2,
                  const float* __restrict__ xW3, const float* __restrict__ xb3,
                  const float* __restrict__ cW1, const float* __restrict__ cb1,
                  const float* __restrict__ cW2, const float* __restrict__ cb2,
                  const float* __restrict__ cW3, const float* __restrict__ cb3,
                  const float* __restrict__ nW,  const float* __restrict__ nb,
                  float* __restrict__ out, int nelem)
{
    __shared__ __align__(16) float sm[SMEM_TOT];
    const int t = threadIdx.x;

    // ---- cooperative weight staging (once per block, ~2.8 KB) ----
    for (int idx = t; idx < 120; idx += 256) {
        int r = idx / 12, c = idx - r * 12;
        sm[OFF_EW1 + idx] = (c < 10) ? eW1[r * 10 + c] : 0.0f;
    }
    for (int idx = t; idx < 120; idx += 256) {
        int r = idx / 12, c = idx - r * 12;
        sm[OFF_EW2 + idx] = (c < 10) ? eW2[r * 10 + c] : 0.0f;
    }
    for (int idx = t; idx < 120; idx += 256) {
        int r = idx / 12, c = idx - r * 12;
        sm[OFF_CW1 + idx] = (c < 10) ? cW1[r * 10 + c] : 0.0f;
    }
    for (int idx = t; idx < 120; idx += 256) {
        int r = idx / 12, c = idx - r * 12;
        sm[OFF_CW2 + idx] = (c < 10) ? cW2[r * 10 + c] : 0.0f;
    }
    if (t < 64)  sm[OFF_XW1 + t] = xW1[t];
    if (t >= 64 && t < 128) sm[OFF_XW2 + (t - 64)] = xW2[t - 64];
    if (t < 10) {
        sm[OFF_EW3 + t] = eW3[t];
        sm[OFF_CW3 + t] = cW3[t];
        sm[OFF_EB1 + t] = eb1[t];
        sm[OFF_EB2 + t] = eb2[t];
        sm[OFF_CB1 + t] = cb1[t];
        sm[OFF_CB2 + t] = cb2[t];
    }
    if (t < 8) {
        sm[OFF_XW3 + t] = xW3[t];
        sm[OFF_XB1 + t] = xb1[t];
        sm[OFF_XB2 + t] = xb2[t];
    }
    if (t == 0) {
        sm[OFF_SC + 0] = eb3[0];
        sm[OFF_SC + 1] = cb3[0];
        sm[OFF_SC + 2] = xb3[0];
        sm[OFF_SC + 3] = nW[0];
        sm[OFF_SC + 4] = nb[0];
    }
    __syncthreads();

    const int b = blockIdx.x * 256 + t;
    if (b >= nelem) return;

    // ---- input loads: contiguous per element, float4 vectorized ----
    float xe[40];
    {
        const float4* p = reinterpret_cast<const float4*>(edge) + (size_t)b * 10;
        #pragma unroll
        for (int j = 0; j < 10; ++j) {
            float4 v = p[j];
            xe[4 * j + 0] = v.x; xe[4 * j + 1] = v.y;
            xe[4 * j + 2] = v.z; xe[4 * j + 3] = v.w;
        }
    }
    float xx[32];
    {
        const float4* p = reinterpret_cast<const float4*>(cross_) + (size_t)b * 8;
        #pragma unroll
        for (int j = 0; j < 8; ++j) {
            float4 v = p[j];
            xx[4 * j + 0] = v.x; xx[4 * j + 1] = v.y;
            xx[4 * j + 2] = v.z; xx[4 * j + 3] = v.w;
        }
    }
    float xc[40];
    {
        const float4* p = reinterpret_cast<const float4*>(corner) + (size_t)b * 10;
        #pragma unroll
        for (int j = 0; j < 10; ++j) {
            float4 v = p[j];
            xc[4 * j + 0] = v.x; xc[4 * j + 1] = v.y;
            xc[4 * j + 2] = v.z; xc[4 * j + 3] = v.w;
        }
    }
    const float cnv = cn[b];

    // ---- three MLPs + scalar affine ----
    const float e  = mlp3_sum4<10, 12>(xe, sm + OFF_EW1, sm + OFF_EB1,
                                           sm + OFF_EW2, sm + OFF_EB2,
                                           sm + OFF_EW3, sm[OFF_SC + 0]);
    const float xr = mlp3_sum4<8, 8>  (xx, sm + OFF_XW1, sm + OFF_XB1,
                                           sm + OFF_XW2, sm + OFF_XB2,
                                           sm + OFF_XW3, sm[OFF_SC + 2]);
    const float cr = mlp3_sum4<10, 12>(xc, sm + OFF_CW1, sm + OFF_CB1,
                                           sm + OFF_CW2, sm + OFF_CB2,
                                           sm + OFF_CW3, sm[OFF_SC + 1]);
    const float n  = fmaf(cnv, sm[OFF_SC + 3], sm[OFF_SC + 4]);

    out[b] = e + xr + cr + n;
}

extern "C" void kernel_launch(void* const* d_in, const int* in_sizes, int n_in,
                              void* d_out, int out_size, void* d_ws, size_t ws_size,
                              hipStream_t stream) {
    const float* edge   = (const float*)d_in[0];
    const float* cross_ = (const float*)d_in[1];
    const float* corner = (const float*)d_in[2];
    const float* cn     = (const float*)d_in[3];
    const float* eW1 = (const float*)d_in[4];
    const float* eb1 = (const float*)d_in[5];
    const float* eW2 = (const float*)d_in[6];
    const float* eb2 = (const float*)d_in[7];
    const float* eW3 = (const float*)d_in[8];
    const float* eb3 = (const float*)d_in[9];
    const float* xW1 = (const float*)d_in[10];
    const float* xb1 = (const float*)d_in[11];
    const float* xW2 = (const float*)d_in[12];
    const float* xb2 = (const float*)d_in[13];
    const float* xW3 = (const float*)d_in[14];
    const float* xb3 = (const float*)d_in[15];
    const float* cW1 = (const float*)d_in[16];
    const float* cb1 = (const float*)d_in[17];
    const float* cW2 = (const float*)d_in[18];
    const float* cb2 = (const float*)d_in[19];
    const float* cW3 = (const float*)d_in[20];
    const float* cb3 = (const float*)d_in[21];
    const float* nW  = (const float*)d_in[22];
    const float* nb  = (const float*)d_in[23];

    const int nelem = in_sizes[3];           // cn is [B,1] -> B elements
    const int grid  = (nelem + 255) / 256;

    osero_kernel<<<grid, 256, 0, stream>>>(edge, cross_, corner, cn,
                                           eW1, eb1, eW2, eb2, eW3, eb3,
                                           xW1, xb1, xW2, xb2, xW3, xb3,
                                           cW1, cb1, cW2, cb2, cW3, cb3,
                                           nW, nb,
                                           (float*)d_out, nelem);
}

// Round 2
// 452.168 us; speedup vs baseline: 1.0239x; 1.0239x over previous
//
#include <hip/hip_runtime.h>

// ---------------------------------------------------------------------------
// OseroNetworks, round 2.
// Grid (B/256, 3): y=0 edge, y=1 corner, y=2 cross(+cn term).
// Each block stages its 256 elements into LDS with COALESCED float4 loads
// (fixes the 160B-lane-stride scatter: 64 distinct lines per vmem instr),
// padded element stride breaks LDS bank conflicts. Weights are read with
// uniform addresses -> scalar loads (SGPR operands, no LDS).
// Packed f32x2 math targets v_pk_fma_f32. Partials summed with HW fp32
// atomic add after an async memset.
// ---------------------------------------------------------------------------

typedef float f2 __attribute__((ext_vector_type(2)));

// Stage 256 elements x (4*F4) floats, coalesced, into LDS rows of PSTR floats.
template<int F4, int PSTR>
__device__ __forceinline__ void stage(const float* __restrict__ in,
                                      float* __restrict__ sm, int t, int blk)
{
    const float4* src = reinterpret_cast<const float4*>(in) + (size_t)blk * (256 * F4);
    #pragma unroll
    for (int it = 0; it < F4; ++it) {
        const int g = it * 256 + t;          // granule index within block tile
        float4 v = src[g];                   // coalesced: lane t -> granule t
        const int e = g / F4;                // element within block (const divisor)
        const int j = g - e * F4;            // float4 within element
        *reinterpret_cast<float4*>(sm + e * PSTR + j * 4) = v;
    }
}

// 3-layer MLP over 4 slices, summed. xl points at this thread's element in
// LDS (4*D contiguous floats). Weights via uniform (scalar) global loads.
template<int D>
__device__ __forceinline__ float mlp4(const float* __restrict__ xl,
                                      const float* __restrict__ W1,
                                      const float* __restrict__ b1,
                                      const float* __restrict__ W2,
                                      const float* __restrict__ b2,
                                      const float* __restrict__ W3,
                                      const float* __restrict__ b3)
{
    constexpr int H = D / 2;
    f2 oacc = {0.0f, 0.0f};
    #pragma unroll
    for (int s = 0; s < 4; ++s) {
        f2 xs[H];
        #pragma unroll
        for (int k = 0; k < H; ++k)
            xs[k] = *reinterpret_cast<const f2*>(xl + s * D + 2 * k);   // b64 LDS

        f2 h1[H];                                   // outputs o=2*op, 2*op+1
        #pragma unroll
        for (int op = 0; op < H; ++op) {
            f2 a = {b1[2 * op], b1[2 * op + 1]};
            #pragma unroll
            for (int i = 0; i < D; ++i) {
                const float xv = (i & 1) ? xs[i >> 1].y : xs[i >> 1].x;
                const f2 w = {W1[(2 * op) * D + i], W1[(2 * op + 1) * D + i]};
                a = __builtin_elementwise_fma(w, (f2){xv, xv}, a);
            }
            h1[op] = __builtin_elementwise_max(a, (f2){0.0f, 0.0f});
        }

        f2 h2[H];
        #pragma unroll
        for (int op = 0; op < H; ++op) {
            f2 a = {b2[2 * op], b2[2 * op + 1]};
            #pragma unroll
            for (int i = 0; i < D; ++i) {
                const float hv = (i & 1) ? h1[i >> 1].y : h1[i >> 1].x;
                const f2 w = {W2[(2 * op) * D + i], W2[(2 * op + 1) * D + i]};
                a = __builtin_elementwise_fma(w, (f2){hv, hv}, a);
            }
            h2[op] = __builtin_elementwise_max(a, (f2){0.0f, 0.0f});
        }

        #pragma unroll
        for (int k = 0; k < H; ++k) {
            const f2 w3 = {W3[2 * k], W3[2 * k + 1]};
            oacc = __builtin_elementwise_fma(w3, h2[k], oacc);
        }
    }
    return oacc.x + oacc.y + 4.0f * b3[0];
}

__global__ __launch_bounds__(256)
void osero_kernel(const float* __restrict__ edge,
                  const float* __restrict__ cross_,
                  const float* __restrict__ corner,
                  const float* __restrict__ cn,
                  const float* __restrict__ eW1, const float* __restrict__ eb1,
                  const float* __restrict__ eW2, const float* __restrict__ eb2,
                  const float* __restrict__ eW3, const float* __restrict__ eb3,
                  const float* __restrict__ xW1, const float* __restrict__ xb1,
                  const float* __restrict__ xW2, const float* __restrict__ xb2,
                  const float* __restrict__ xW3, const float* __restrict__ xb3,
                  const float* __restrict__ cW1, const float* __restrict__ cb1,
                  const float* __restrict__ cW2, const float* __restrict__ cb2,
                  const float* __restrict__ cW3, const float* __restrict__ cb3,
                  const float* __restrict__ nW,  const float* __restrict__ nb,
                  float* __restrict__ out)
{
    // 44-float element stride (16B aligned; bank starts 12t%32 -> 8 groups).
    __shared__ __align__(16) float sm[256 * 44];

    const int t   = threadIdx.x;
    const int blk = blockIdx.x;
    const int y   = blockIdx.y;
    const int b   = blk * 256 + t;

    float val;
    if (y == 0) {
        stage<10, 44>(edge, sm, t, blk);
        __syncthreads();
        val = mlp4<10>(sm + t * 44, eW1, eb1, eW2, eb2, eW3, eb3);
    } else if (y == 1) {
        stage<10, 44>(corner, sm, t, blk);
        __syncthreads();
        val = mlp4<10>(sm + t * 44, cW1, cb1, cW2, cb2, cW3, cb3);
    } else {
        stage<8, 36>(cross_, sm, t, blk);
        __syncthreads();
        val = mlp4<8>(sm + t * 36, xW1, xb1, xW2, xb2, xW3, xb3);
        val += fmaf(cn[b], nW[0], nb[0]);     // coalesced 4B/lane load
    }

    // HW fp32 atomic add (out is coarse-grained device memory).
    unsafeAtomicAdd(out + b, val);
}

extern "C" void kernel_launch(void* const* d_in, const int* in_sizes, int n_in,
                              void* d_out, int out_size, void* d_ws, size_t ws_size,
                              hipStream_t stream) {
    const float* edge   = (const float*)d_in[0];
    const float* cross_ = (const float*)d_in[1];
    const float* corner = (const float*)d_in[2];
    const float* cn     = (const float*)d_in[3];
    const float* eW1 = (const float*)d_in[4];
    const float* eb1 = (const float*)d_in[5];
    const float* eW2 = (const float*)d_in[6];
    const float* eb2 = (const float*)d_in[7];
    const float* eW3 = (const float*)d_in[8];
    const float* eb3 = (const float*)d_in[9];
    const float* xW1 = (const float*)d_in[10];
    const float* xb1 = (const float*)d_in[11];
    const float* xW2 = (const float*)d_in[12];
    const float* xb2 = (const float*)d_in[13];
    const float* xW3 = (const float*)d_in[14];
    const float* xb3 = (const float*)d_in[15];
    const float* cW1 = (const float*)d_in[16];
    const float* cb1 = (const float*)d_in[17];
    const float* cW2 = (const float*)d_in[18];
    const float* cb2 = (const float*)d_in[19];
    const float* cW3 = (const float*)d_in[20];
    const float* cb3 = (const float*)d_in[21];
    const float* nW  = (const float*)d_in[22];
    const float* nb  = (const float*)d_in[23];

    const int nelem = in_sizes[3];               // cn is [B,1] -> B
    const int nblk  = (nelem + 255) / 256;       // B divisible by 256

    hipMemsetAsync(d_out, 0, (size_t)out_size * sizeof(float), stream);

    dim3 grid(nblk, 3);
    osero_kernel<<<grid, 256, 0, stream>>>(edge, cross_, corner, cn,
                                           eW1, eb1, eW2, eb2, eW3, eb3,
                                           xW1, xb1, xW2, xb2, xW3, xb3,
                                           cW1, cb1, cW2, cb2, cW3, cb3,
                                           nW, nb, (float*)d_out);
}